// Round 11
// baseline (964.866 us; speedup 1.0000x reference)
//
#include <hip/hip_runtime.h>
#include <math.h>

#define N_NODES 50000
#define N_EDGES 1600000
#define NB      391          // ceil(50000/128) buckets of 128 nodes

__device__ __forceinline__ float lrelu02(float x) { return x > 0.f ? x : 0.2f * x; }
__device__ __forceinline__ float elu1(float x)    { return x > 0.f ? x : __expf(x) - 1.f; }

// bf16 helpers (RNE pack)
__device__ __forceinline__ unsigned short f2bf(float f) {
    unsigned int u = __float_as_uint(f);
    return (unsigned short)((u + 0x7fffu + ((u >> 16) & 1u)) >> 16);
}
__device__ __forceinline__ float2 bfp2(unsigned int u) {
    float2 r;
    r.x = __uint_as_float(u << 16);
    r.y = __uint_as_float(u & 0xffff0000u);
    return r;
}

// ------- GEMM layers 1/2 (FOUT=64) fused with attention logits -------
// h written HEAD-MAJOR: h16[hd][node][16] bf16 (per-head slice = 1.6 MB, L2-resident)
template<int FIN>
__global__ void gemm_al_kernel(const float* __restrict__ x, const float* __restrict__ W,
                               const float* __restrict__ a_s, const float* __restrict__ a_d,
                               unsigned short* __restrict__ h,
                               float* __restrict__ al_s, float* __restrict__ al_d) {
    __shared__ float Wl[FIN][64];
    __shared__ unsigned short ot[32][66];   // +2 pad
    const int tx = threadIdx.x, ty = threadIdx.y;
    const int tid = ty * 64 + tx;
    for (int i = tid; i < FIN * 64; i += 256) {
        int k = i >> 6, f = i & 63;
        Wl[k][f] = W[(size_t)k * 64 + f];
    }
    __syncthreads();
    const int n0b = blockIdx.x * 32;
    const int n0 = n0b + ty * 8;
    float acc[8] = {0.f, 0.f, 0.f, 0.f, 0.f, 0.f, 0.f, 0.f};
    if (n0 + 8 <= N_NODES) {
        for (int k = 0; k < FIN; k += 4) {
            float4 xv[8];
#pragma unroll
            for (int i = 0; i < 8; ++i)
                xv[i] = *(const float4*)(x + (size_t)(n0 + i) * FIN + k);
#pragma unroll
            for (int kk = 0; kk < 4; ++kk) {
                float w = Wl[k + kk][tx];
#pragma unroll
                for (int i = 0; i < 8; ++i) {
                    float xs = (kk == 0) ? xv[i].x : (kk == 1) ? xv[i].y : (kk == 2) ? xv[i].z : xv[i].w;
                    acc[i] = fmaf(xs, w, acc[i]);
                }
            }
        }
    } else {
        for (int i = 0; i < 8; ++i) {
            if (n0 + i >= N_NODES) break;
            const float* xr = x + (size_t)(n0 + i) * FIN;
            float a = 0.f;
            for (int k = 0; k < FIN; ++k) a = fmaf(xr[k], Wl[k][tx], a);
            acc[i] = a;
        }
    }
#pragma unroll
    for (int i = 0; i < 8; ++i) ot[ty * 8 + i][tx] = f2bf(acc[i]);
    __syncthreads();
    int vrows = N_NODES - n0b; if (vrows > 32) vrows = 32;
    {   // head-major writeout: slice stride 400,000 uints, node row 8 uints
        unsigned int* ph = (unsigned int*)h;
        for (int i = tid; i < vrows * 32; i += 256) {
            int row = i >> 5, w = i & 31;
            int hd = w >> 3, c = w & 7;
            ph[hd * 400000 + (size_t)(n0b + row) * 8 + c] =
                *(const unsigned int*)&ot[row][hd * 16 + c * 2];
        }
    }
    if (tid < 128) {
        int node = tid >> 2, hd = tid & 3;
        if (node < vrows) {
            const float* as = a_s + hd * 16;
            const float* ad = a_d + hd * 16;
            float s1 = 0.f, s2 = 0.f;
#pragma unroll
            for (int c = 0; c < 16; c += 2) {
                unsigned int q = *(const unsigned int*)&ot[node][hd * 16 + c];
                float2 p = bfp2(q);
                s1 = fmaf(p.x, as[c], s1);     s2 = fmaf(p.x, ad[c], s2);
                s1 = fmaf(p.y, as[c + 1], s1); s2 = fmaf(p.y, ad[c + 1], s2);
            }
            al_s[(n0b + node) * 4 + hd] = s1;
            al_d[(n0b + node) * 4 + hd] = s2;
        }
    }
}

// ------- L3 GEMM: fused al3; h written HEAD-MAJOR h40[hd][node][40] (4 MB/slice) -------
__global__ void gemm240_kernel(const float* __restrict__ x, const float* __restrict__ W,
                               const float* __restrict__ a_s, const float* __restrict__ a_d,
                               unsigned short* __restrict__ h,
                               float* __restrict__ al_s, float* __restrict__ al_d) {
    __shared__ float Wl[64][240];           // 61440 B
    __shared__ unsigned short ot[32][240];  // 15360 B
    const int tx = threadIdx.x, ty = threadIdx.y;
    const int tid = ty * 64 + tx;
    {
        const float4* W4 = (const float4*)W;
        float4* Wl4 = (float4*)&Wl[0][0];
        for (int i = tid; i < 64 * 240 / 4; i += 256) Wl4[i] = W4[i];
    }
    __syncthreads();
    const int n0b = blockIdx.x * 32;
    const int n0 = n0b + ty * 8;
    float acc[4][8];
#pragma unroll
    for (int g = 0; g < 4; ++g)
#pragma unroll
        for (int i = 0; i < 8; ++i) acc[g][i] = 0.f;
    const int tx3 = (tx < 48) ? (192 + tx) : 0;
    if (n0 + 8 <= N_NODES) {
        for (int k = 0; k < 64; k += 4) {
            float4 xv[8];
#pragma unroll
            for (int i = 0; i < 8; ++i)
                xv[i] = *(const float4*)(x + (size_t)(n0 + i) * 64 + k);
#pragma unroll
            for (int kk = 0; kk < 4; ++kk) {
                float w0 = Wl[k + kk][tx];
                float w1 = Wl[k + kk][64 + tx];
                float w2 = Wl[k + kk][128 + tx];
                float w3 = Wl[k + kk][tx3];
#pragma unroll
                for (int i = 0; i < 8; ++i) {
                    float xs = (kk == 0) ? xv[i].x : (kk == 1) ? xv[i].y : (kk == 2) ? xv[i].z : xv[i].w;
                    acc[0][i] = fmaf(xs, w0, acc[0][i]);
                    acc[1][i] = fmaf(xs, w1, acc[1][i]);
                    acc[2][i] = fmaf(xs, w2, acc[2][i]);
                    acc[3][i] = fmaf(xs, w3, acc[3][i]);
                }
            }
        }
    } else {
        for (int i = 0; i < 8; ++i) {
            if (n0 + i >= N_NODES) break;
            const float* xr = x + (size_t)(n0 + i) * 64;
            for (int k = 0; k < 64; ++k) {
                float xs = xr[k];
                acc[0][i] = fmaf(xs, Wl[k][tx], acc[0][i]);
                acc[1][i] = fmaf(xs, Wl[k][64 + tx], acc[1][i]);
                acc[2][i] = fmaf(xs, Wl[k][128 + tx], acc[2][i]);
                acc[3][i] = fmaf(xs, Wl[k][tx3], acc[3][i]);
            }
        }
    }
#pragma unroll
    for (int i = 0; i < 8; ++i) {
        ot[ty * 8 + i][tx] = f2bf(acc[0][i]);
        ot[ty * 8 + i][64 + tx] = f2bf(acc[1][i]);
        ot[ty * 8 + i][128 + tx] = f2bf(acc[2][i]);
        if (tx < 48) ot[ty * 8 + i][192 + tx] = f2bf(acc[3][i]);
    }
    __syncthreads();
    int vrows = N_NODES - n0b; if (vrows > 32) vrows = 32;
    {   // head-major writeout: slice stride 1,000,000 uints, node row 20 uints
        unsigned int* ph = (unsigned int*)h;
        for (int i = tid; i < vrows * 120; i += 256) {
            int row = i / 120, w = i - row * 120;
            int hd = w / 20, c = w - hd * 20;
            ph[hd * 1000000 + (size_t)(n0b + row) * 20 + c] =
                *(const unsigned int*)&ot[row][hd * 40 + c * 2];
        }
    }
    if (tid < 192) {
        int node = tid / 6, hd = tid % 6;
        if (node < vrows) {
            const unsigned short* r = &ot[node][hd * 40];
            const float* as = a_s + hd * 40;
            const float* ad = a_d + hd * 40;
            float s1 = 0.f, s2 = 0.f;
            for (int c = 0; c < 40; c += 2) {
                unsigned int q = *(const unsigned int*)(r + c);
                float2 p = bfp2(q);
                s1 = fmaf(p.x, as[c], s1);     s2 = fmaf(p.x, ad[c], s2);
                s1 = fmaf(p.y, as[c + 1], s1); s2 = fmaf(p.y, ad[c + 1], s2);
            }
            al_s[(n0b + node) * 6 + hd] = s1;
            al_d[(n0b + node) * 6 + hd] = s2;
        }
    }
}

// ---------------- CSR build ----------------
__global__ void deg_kernel(const int* __restrict__ ei, int* __restrict__ deg) {
    int e = blockIdx.x * 256 + threadIdx.x;
    if (e >= N_EDGES) return;
    atomicAdd(&deg[ei[N_EDGES + e]], 1);
}

__global__ void scan_kernel(const int* __restrict__ deg, int* __restrict__ rowptr) {
    __shared__ int wsum[16];
    const int t = threadIdx.x;
    const int PER = (N_NODES + 1023) / 1024;  // 49
    const int base = t * PER;
    int s = 0;
    for (int i = 0; i < PER; ++i) { int idx = base + i; if (idx < N_NODES) s += deg[idx]; }
    const int lane = t & 63, wv = t >> 6;
    int v = s;
#pragma unroll
    for (int off = 1; off < 64; off <<= 1) {
        int u = __shfl_up(v, off);
        if (lane >= off) v += u;
    }
    if (lane == 63) wsum[wv] = v;
    __syncthreads();
    if (wv == 0 && lane < 16) {
        int u = wsum[lane];
#pragma unroll
        for (int off = 1; off < 16; off <<= 1) {
            int p = __shfl_up(u, off);
            if (lane >= off) u += p;
        }
        wsum[lane] = u;
    }
    __syncthreads();
    int run = v - s + (wv ? wsum[wv - 1] : 0);   // exclusive prefix
    if (t == 1023) rowptr[N_NODES] = wsum[15];
    for (int i = 0; i < PER; ++i) {
        int idx = base + i;
        if (idx < N_NODES) {
            rowptr[idx] = run;
            run += deg[idx];
        }
    }
}

__global__ void initcur_kernel(const int* __restrict__ rowptr, int* __restrict__ bcur) {
    int b = blockIdx.x * 256 + threadIdx.x;
    if (b < NB) bcur[b * 16] = rowptr[b * 128];
}

__global__ void bucket_kernel(const int* __restrict__ ei, int* __restrict__ bcur,
                              unsigned int* __restrict__ stage) {
    int e = blockIdx.x * 256 + threadIdx.x;
    if (e >= N_EDGES) return;
    int src = ei[e], dst = ei[N_EDGES + e];
    int pos = atomicAdd(&bcur[(dst >> 7) * 16], 1);
    stage[pos] = ((unsigned int)(dst & 127) << 16) | (unsigned int)src;
}

__global__ void place_kernel(const int* __restrict__ rowptr, const unsigned int* __restrict__ stage,
                             unsigned short* __restrict__ csr) {
    __shared__ int cur[128];
    const int b = blockIdx.x;
    const int n0 = b * 128;
    const int t = threadIdx.x;
    if (t < 128) {
        int n = n0 + t;
        cur[t] = (n < N_NODES) ? rowptr[n] : 0;
    }
    __syncthreads();
    int beg = rowptr[n0];
    int nend = n0 + 128; if (nend > N_NODES) nend = N_NODES;
    int end = rowptr[nend];
    for (int i = beg + t; i < end; i += 256) {
        unsigned int v = stage[i];
        int pos = atomicAdd(&cur[v >> 16], 1);
        csr[pos] = (unsigned short)(v & 0xFFFFu);
    }
}

// ------- agg layers 1/2, PER-HEAD (grid.y = head): 16 edge-groups x 4 lanes -------
// Per wave instr: 16 edges, 16x32B h gathers from a 1.6MB L2-resident slice.
__global__ void agg16_kernel(const int* __restrict__ rowptr, const unsigned short* __restrict__ csr_src,
                             const float* __restrict__ al_s, const float* __restrict__ al_d,
                             const unsigned short* __restrict__ h16, const float* __restrict__ b,
                             float* __restrict__ xn) {
    const int hd = blockIdx.y;
    int node = blockIdx.x * 4 + (threadIdx.x >> 6);   // grid.x exact
    int lane = threadIdx.x & 63;
    int g = lane >> 2;          // edge group 0..15
    int l = lane & 3;           // channel quad, c0 = l*4
    const unsigned short* hs = h16 + (size_t)hd * (N_NODES * 16);
    float ald = al_d[node * 4 + hd];
    int beg = rowptr[node], end = rowptr[node + 1];
    float denom = 0.f;
    float a0 = 0.f, a1 = 0.f, a2 = 0.f, a3 = 0.f;
    if (g == 0) {   // self loop
        float w = __expf(lrelu02(al_s[node * 4 + hd] + ald));
        uint2 q = *(const uint2*)(hs + (size_t)node * 16 + l * 4);
        float2 ab = bfp2(q.x), cd = bfp2(q.y);
        denom = w; a0 = w * ab.x; a1 = w * ab.y; a2 = w * cd.x; a3 = w * cd.y;
    }
    for (int j = beg + g; j < end; j += 16) {
        int src = csr_src[j];
        float w = __expf(lrelu02(al_s[src * 4 + hd] + ald));
        uint2 q = *(const uint2*)(hs + (size_t)src * 16 + l * 4);
        denom += w;
        float2 ab = bfp2(q.x), cd = bfp2(q.y);
        a0 = fmaf(w, ab.x, a0); a1 = fmaf(w, ab.y, a1);
        a2 = fmaf(w, cd.x, a2); a3 = fmaf(w, cd.y, a3);
    }
#pragma unroll
    for (int m = 4; m <= 32; m <<= 1) {
        denom += __shfl_xor(denom, m);
        a0 += __shfl_xor(a0, m); a1 += __shfl_xor(a1, m);
        a2 += __shfl_xor(a2, m); a3 += __shfl_xor(a3, m);
    }
    if (g == 0) {
        float r = 1.f / denom;
        int cb = hd * 16 + l * 4;
        float4 o;
        o.x = elu1(a0 * r + b[cb]);
        o.y = elu1(a1 * r + b[cb + 1]);
        o.z = elu1(a2 * r + b[cb + 2]);
        o.w = elu1(a3 * r + b[cb + 3]);
        *(float4*)(xn + (size_t)node * 64 + cb) = o;
    }
}

// ------- agg layer 3, PER-HEAD (grid.y = head): 4 edge-groups x 16 lanes -------
// Per-head slice = 4 MB (= one XCD L2). Writes out40[hd][node][40] fp32.
__global__ void agg40_kernel(const int* __restrict__ rowptr, const unsigned short* __restrict__ csr_src,
                             const float* __restrict__ al_s, const float* __restrict__ al_d,
                             const unsigned short* __restrict__ h40, float* __restrict__ out40) {
    const int hd = blockIdx.y;
    int node = blockIdx.x * 4 + (threadIdx.x >> 6);   // grid.x exact
    int lane = threadIdx.x & 63;
    int g = lane >> 4;          // edge group 0..3
    int l = lane & 15;          // active l<10, c0 = l*4
    bool act = l < 10;
    int c0 = act ? l * 4 : 0;
    const unsigned short* hs = h40 + (size_t)hd * (N_NODES * 40);
    float ald = al_d[node * 6 + hd];
    int beg = rowptr[node], end = rowptr[node + 1];
    float denom = 0.f;
    float a0 = 0.f, a1 = 0.f, a2 = 0.f, a3 = 0.f;
    if (g == 0) {   // self loop
        float w = __expf(lrelu02(al_s[node * 6 + hd] + ald));
        uint2 q = *(const uint2*)(hs + (size_t)node * 40 + c0);
        float2 ab = bfp2(q.x), cd = bfp2(q.y);
        denom = w; a0 = w * ab.x; a1 = w * ab.y; a2 = w * cd.x; a3 = w * cd.y;
    }
    for (int j = beg + g; j < end; j += 4) {
        int src = csr_src[j];
        float w = __expf(lrelu02(al_s[src * 6 + hd] + ald));
        uint2 q = *(const uint2*)(hs + (size_t)src * 40 + c0);
        denom += w;
        float2 ab = bfp2(q.x), cd = bfp2(q.y);
        a0 = fmaf(w, ab.x, a0); a1 = fmaf(w, ab.y, a1);
        a2 = fmaf(w, cd.x, a2); a3 = fmaf(w, cd.y, a3);
    }
#pragma unroll
    for (int m = 16; m <= 32; m <<= 1) {
        denom += __shfl_xor(denom, m);
        a0 += __shfl_xor(a0, m); a1 += __shfl_xor(a1, m);
        a2 += __shfl_xor(a2, m); a3 += __shfl_xor(a3, m);
    }
    if (g == 0 && act) {
        float r = 1.f / denom;
        float4 o;
        o.x = a0 * r; o.y = a1 * r; o.z = a2 * r; o.w = a3 * r;
        *(float4*)(out40 + (size_t)hd * (N_NODES * 40) + (size_t)node * 40 + c0) = o;
    }
}

// ------- final: head-mean + bias + ELU + log_softmax -------
__global__ void final40_kernel(const float* __restrict__ out40, const float* __restrict__ b3,
                               float* __restrict__ y) {
    int node = blockIdx.x * 4 + (threadIdx.x >> 6);
    int lane = threadIdx.x & 63;
    float v;
    if (lane < 40) {
        float s = 0.f;
#pragma unroll
        for (int hh = 0; hh < 6; ++hh)
            s += out40[(size_t)hh * (N_NODES * 40) + (size_t)node * 40 + lane];
        v = elu1(s * (1.f / 6.f) + b3[lane]);
    } else {
        v = -INFINITY;
    }
    float m = v;
#pragma unroll
    for (int o = 32; o > 0; o >>= 1) m = fmaxf(m, __shfl_xor(m, o));
    float ex = (lane < 40) ? __expf(v - m) : 0.f;
    float ssum = ex;
#pragma unroll
    for (int o = 32; o > 0; o >>= 1) ssum += __shfl_xor(ssum, o);
    if (lane < 40) y[(size_t)node * 40 + lane] = v - m - __logf(ssum);
}

extern "C" void kernel_launch(void* const* d_in, const int* in_sizes, int n_in,
                              void* d_out, int out_size, void* d_ws, size_t ws_size,
                              hipStream_t stream) {
    const float* x   = (const float*)d_in[0];
    const int*   ei  = (const int*)d_in[1];   // [2, E]
    const float* W1  = (const float*)d_in[2];
    const float* a1s = (const float*)d_in[3];
    const float* a1d = (const float*)d_in[4];
    const float* b1  = (const float*)d_in[5];
    const float* W2  = (const float*)d_in[6];
    const float* a2s = (const float*)d_in[7];
    const float* a2d = (const float*)d_in[8];
    const float* b2  = (const float*)d_in[9];
    const float* W3  = (const float*)d_in[10];
    const float* a3s = (const float*)d_in[11];
    const float* a3d = (const float*)d_in[12];
    const float* b3  = (const float*)d_in[13];
    float* y = (float*)d_out;

    float* ws      = (float*)d_ws;
    unsigned short* h_bf = (unsigned short*)ws;               // 12,000,000 ushort (head-major)
    float* x_buf   = ws + 6000000;                            //  3,200,000 floats
    float* al_s    = ws + 9200000;                            //    300,000
    float* al_d    = ws + 9500000;                            //    300,000
    int*   deg     = (int*)(ws + 9800000);                    //     50,000
    int*   rowptr  = (int*)(ws + 9850000);                    //     50,001
    unsigned short* csr_src = (unsigned short*)(ws + 9900008);  // 1.6M ushort
    unsigned int* stage = (unsigned int*)(ws + 10700008);     // 1.6M uint
    int* bcur = (int*)(ws + 12300008);                        // NB*16 ints
    float* out40 = ws + 12306264;                             // 12,000,000 floats
    // total ~24.3M floats = 97.2 MB

    // ---- CSR build via bucketed counting sort (once; shared by all 3 layers) ----
    hipMemsetAsync(deg, 0, N_NODES * sizeof(int), stream);
    deg_kernel<<<(N_EDGES + 255) / 256, 256, 0, stream>>>(ei, deg);
    scan_kernel<<<1, 1024, 0, stream>>>(deg, rowptr);
    initcur_kernel<<<(NB + 255) / 256, 256, 0, stream>>>(rowptr, bcur);
    bucket_kernel<<<(N_EDGES + 255) / 256, 256, 0, stream>>>(ei, bcur, stage);
    place_kernel<<<NB, 256, 0, stream>>>(rowptr, stage, csr_src);

    const int nblk = N_NODES / 4;                  // 12500, exact
    const int gemm_gx = (N_NODES + 31) / 32;
    dim3 gblk(64, 4);

    // ---- layer 1: 128 -> (4,16) concat ----
    gemm_al_kernel<128><<<gemm_gx, gblk, 0, stream>>>(x, W1, a1s, a1d, h_bf, al_s, al_d);
    agg16_kernel<<<dim3(nblk, 4), 256, 0, stream>>>(rowptr, csr_src, al_s, al_d, h_bf, b1, x_buf);

    // ---- layer 2: 64 -> (4,16) concat ----
    gemm_al_kernel<64><<<gemm_gx, gblk, 0, stream>>>(x_buf, W2, a2s, a2d, h_bf, al_s, al_d);
    agg16_kernel<<<dim3(nblk, 4), 256, 0, stream>>>(rowptr, csr_src, al_s, al_d, h_bf, b2, x_buf);

    // ---- layer 3: 64 -> (6,40) mean ----
    gemm240_kernel<<<gemm_gx, gblk, 0, stream>>>(x_buf, W3, a3s, a3d, h_bf, al_s, al_d);
    agg40_kernel<<<dim3(nblk, 6), 256, 0, stream>>>(rowptr, csr_src, al_s, al_d, h_bf, out40);
    final40_kernel<<<nblk, 256, 0, stream>>>(out40, b3, y);
}

// Round 12
// 671.505 us; speedup vs baseline: 1.4369x; 1.4369x over previous
//
#include <hip/hip_runtime.h>
#include <math.h>

#define N_NODES 50000
#define N_EDGES 1600000
#define NB      391          // ceil(50000/128) buckets of 128 nodes

typedef __attribute__((ext_vector_type(2))) float v2f;

__device__ __forceinline__ float lrelu02(float x) { return x > 0.f ? x : 0.2f * x; }
__device__ __forceinline__ float elu1(float x)    { return x > 0.f ? x : __expf(x) - 1.f; }

// bf16 helpers (RNE pack)
__device__ __forceinline__ unsigned short f2bf(float f) {
    unsigned int u = __float_as_uint(f);
    return (unsigned short)((u + 0x7fffu + ((u >> 16) & 1u)) >> 16);
}
__device__ __forceinline__ float2 bfp2(unsigned int u) {
    float2 r;
    r.x = __uint_as_float(u << 16);
    r.y = __uint_as_float(u & 0xffff0000u);
    return r;
}

// ------- GEMM layers 1/2 (FOUT=64) fused with attention logits (R9 form) -------
template<int FIN>
__global__ void gemm_al_kernel(const float* __restrict__ x, const float* __restrict__ W,
                               const float* __restrict__ a_s, const float* __restrict__ a_d,
                               unsigned short* __restrict__ h,
                               float* __restrict__ al_s, float* __restrict__ al_d) {
    __shared__ float Wl[FIN][64];
    __shared__ unsigned short ot[32][66];   // +2 pad
    const int tx = threadIdx.x, ty = threadIdx.y;
    const int tid = ty * 64 + tx;
    for (int i = tid; i < FIN * 64; i += 256) {
        int k = i >> 6, f = i & 63;
        Wl[k][f] = W[(size_t)k * 64 + f];
    }
    __syncthreads();
    const int n0b = blockIdx.x * 32;
    const int n0 = n0b + ty * 8;
    float acc[8] = {0.f, 0.f, 0.f, 0.f, 0.f, 0.f, 0.f, 0.f};
    if (n0 + 8 <= N_NODES) {
        for (int k = 0; k < FIN; k += 4) {
            float4 xv[8];
#pragma unroll
            for (int i = 0; i < 8; ++i)
                xv[i] = *(const float4*)(x + (size_t)(n0 + i) * FIN + k);
#pragma unroll
            for (int kk = 0; kk < 4; ++kk) {
                float w = Wl[k + kk][tx];
#pragma unroll
                for (int i = 0; i < 8; ++i) {
                    float xs = (kk == 0) ? xv[i].x : (kk == 1) ? xv[i].y : (kk == 2) ? xv[i].z : xv[i].w;
                    acc[i] = fmaf(xs, w, acc[i]);
                }
            }
        }
    } else {
        for (int i = 0; i < 8; ++i) {
            if (n0 + i >= N_NODES) break;
            const float* xr = x + (size_t)(n0 + i) * FIN;
            float a = 0.f;
            for (int k = 0; k < FIN; ++k) a = fmaf(xr[k], Wl[k][tx], a);
            acc[i] = a;
        }
    }
#pragma unroll
    for (int i = 0; i < 8; ++i) ot[ty * 8 + i][tx] = f2bf(acc[i]);
    __syncthreads();
    int vrows = N_NODES - n0b; if (vrows > 32) vrows = 32;
    {   // node-major coalesced writeout
        unsigned int* ph = (unsigned int*)(h + (size_t)n0b * 64);
        for (int i = tid; i < vrows * 32; i += 256) {
            int row = i >> 5, col = i & 31;
            ph[i] = *(const unsigned int*)&ot[row][col * 2];
        }
    }
    if (tid < 128) {
        int node = tid >> 2, hd = tid & 3;
        if (node < vrows) {
            const float* as = a_s + hd * 16;
            const float* ad = a_d + hd * 16;
            float s1 = 0.f, s2 = 0.f;
#pragma unroll
            for (int c = 0; c < 16; c += 2) {
                unsigned int q = *(const unsigned int*)&ot[node][hd * 16 + c];
                float2 p = bfp2(q);
                s1 = fmaf(p.x, as[c], s1);     s2 = fmaf(p.x, ad[c], s2);
                s1 = fmaf(p.y, as[c + 1], s1); s2 = fmaf(p.y, ad[c + 1], s2);
            }
            al_s[(n0b + node) * 4 + hd] = s1;
            al_d[(n0b + node) * 4 + hd] = s2;
        }
    }
}

// ------- L3 GEMM: fused al3; h written as FP8 e4m3, 256B-aligned rows (64 uints) -------
__global__ void gemm240_kernel(const float* __restrict__ x, const float* __restrict__ W,
                               const float* __restrict__ a_s, const float* __restrict__ a_d,
                               unsigned int* __restrict__ h8,
                               float* __restrict__ al_s, float* __restrict__ al_d) {
    __shared__ float Wl[64][240];           // 61440 B
    __shared__ unsigned short ot[32][240];  // 15360 B
    const int tx = threadIdx.x, ty = threadIdx.y;
    const int tid = ty * 64 + tx;
    {
        const float4* W4 = (const float4*)W;
        float4* Wl4 = (float4*)&Wl[0][0];
        for (int i = tid; i < 64 * 240 / 4; i += 256) Wl4[i] = W4[i];
    }
    __syncthreads();
    const int n0b = blockIdx.x * 32;
    const int n0 = n0b + ty * 8;
    float acc[4][8];
#pragma unroll
    for (int g = 0; g < 4; ++g)
#pragma unroll
        for (int i = 0; i < 8; ++i) acc[g][i] = 0.f;
    const int tx3 = (tx < 48) ? (192 + tx) : 0;
    if (n0 + 8 <= N_NODES) {
        for (int k = 0; k < 64; k += 4) {
            float4 xv[8];
#pragma unroll
            for (int i = 0; i < 8; ++i)
                xv[i] = *(const float4*)(x + (size_t)(n0 + i) * 64 + k);
#pragma unroll
            for (int kk = 0; kk < 4; ++kk) {
                float w0 = Wl[k + kk][tx];
                float w1 = Wl[k + kk][64 + tx];
                float w2 = Wl[k + kk][128 + tx];
                float w3 = Wl[k + kk][tx3];
#pragma unroll
                for (int i = 0; i < 8; ++i) {
                    float xs = (kk == 0) ? xv[i].x : (kk == 1) ? xv[i].y : (kk == 2) ? xv[i].z : xv[i].w;
                    acc[0][i] = fmaf(xs, w0, acc[0][i]);
                    acc[1][i] = fmaf(xs, w1, acc[1][i]);
                    acc[2][i] = fmaf(xs, w2, acc[2][i]);
                    acc[3][i] = fmaf(xs, w3, acc[3][i]);
                }
            }
        }
    } else {
        for (int i = 0; i < 8; ++i) {
            if (n0 + i >= N_NODES) break;
            const float* xr = x + (size_t)(n0 + i) * 64;
            for (int k = 0; k < 64; ++k) {
                float xs = xr[k];
                acc[0][i] = fmaf(xs, Wl[k][tx], acc[0][i]);
                acc[1][i] = fmaf(xs, Wl[k][64 + tx], acc[1][i]);
                acc[2][i] = fmaf(xs, Wl[k][128 + tx], acc[2][i]);
                acc[3][i] = fmaf(xs, Wl[k][tx3], acc[3][i]);
            }
        }
    }
#pragma unroll
    for (int i = 0; i < 8; ++i) {
        ot[ty * 8 + i][tx] = f2bf(acc[0][i]);
        ot[ty * 8 + i][64 + tx] = f2bf(acc[1][i]);
        ot[ty * 8 + i][128 + tx] = f2bf(acc[2][i]);
        if (tx < 48) ot[ty * 8 + i][192 + tx] = f2bf(acc[3][i]);
    }
    __syncthreads();
    int vrows = N_NODES - n0b; if (vrows > 32) vrows = 32;
    {   // fp8 writeout: 64 uints per node row (last 4 are zero pad)
        for (int i = tid; i < vrows * 64; i += 256) {
            int row = i >> 6, c = i & 63;
            unsigned int packed = 0;
            if (c < 60) {
                uint2 q = *(const uint2*)&ot[row][c * 4];
                float2 p0 = bfp2(q.x), p1 = bfp2(q.y);
                int lo = __builtin_amdgcn_cvt_pk_fp8_f32(p0.x, p0.y, 0, false);
                packed = (unsigned int)__builtin_amdgcn_cvt_pk_fp8_f32(p1.x, p1.y, lo, true);
            }
            h8[(size_t)(n0b + row) * 64 + c] = packed;
        }
    }
    if (tid < 192) {
        int node = tid / 6, hd = tid % 6;
        if (node < vrows) {
            const unsigned short* r = &ot[node][hd * 40];
            const float* as = a_s + hd * 40;
            const float* ad = a_d + hd * 40;
            float s1 = 0.f, s2 = 0.f;
            for (int c = 0; c < 40; c += 2) {
                unsigned int q = *(const unsigned int*)(r + c);
                float2 p = bfp2(q);
                s1 = fmaf(p.x, as[c], s1);     s2 = fmaf(p.x, ad[c], s2);
                s1 = fmaf(p.y, as[c + 1], s1); s2 = fmaf(p.y, ad[c + 1], s2);
            }
            al_s[(n0b + node) * 6 + hd] = s1;
            al_d[(n0b + node) * 6 + hd] = s2;
        }
    }
}

// ---------------- CSR build (R9 form) ----------------
__global__ void deg_kernel(const int* __restrict__ ei, int* __restrict__ deg) {
    int e = blockIdx.x * 256 + threadIdx.x;
    if (e >= N_EDGES) return;
    atomicAdd(&deg[ei[N_EDGES + e]], 1);
}

__global__ void scan_kernel(const int* __restrict__ deg, int* __restrict__ rowptr) {
    __shared__ int wsum[16];
    const int t = threadIdx.x;
    const int PER = (N_NODES + 1023) / 1024;  // 49
    const int base = t * PER;
    int s = 0;
    for (int i = 0; i < PER; ++i) { int idx = base + i; if (idx < N_NODES) s += deg[idx]; }
    const int lane = t & 63, wv = t >> 6;
    int v = s;
#pragma unroll
    for (int off = 1; off < 64; off <<= 1) {
        int u = __shfl_up(v, off);
        if (lane >= off) v += u;
    }
    if (lane == 63) wsum[wv] = v;
    __syncthreads();
    if (wv == 0 && lane < 16) {
        int u = wsum[lane];
#pragma unroll
        for (int off = 1; off < 16; off <<= 1) {
            int p = __shfl_up(u, off);
            if (lane >= off) u += p;
        }
        wsum[lane] = u;
    }
    __syncthreads();
    int run = v - s + (wv ? wsum[wv - 1] : 0);   // exclusive prefix
    if (t == 1023) rowptr[N_NODES] = wsum[15];
    for (int i = 0; i < PER; ++i) {
        int idx = base + i;
        if (idx < N_NODES) {
            rowptr[idx] = run;
            run += deg[idx];
        }
    }
}

__global__ void initcur_kernel(const int* __restrict__ rowptr, int* __restrict__ bcur) {
    int b = blockIdx.x * 256 + threadIdx.x;
    if (b < NB) bcur[b * 16] = rowptr[b * 128];
}

__global__ void bucket_kernel(const int* __restrict__ ei, int* __restrict__ bcur,
                              unsigned int* __restrict__ stage) {
    int e = blockIdx.x * 256 + threadIdx.x;
    if (e >= N_EDGES) return;
    int src = ei[e], dst = ei[N_EDGES + e];
    int pos = atomicAdd(&bcur[(dst >> 7) * 16], 1);
    stage[pos] = ((unsigned int)(dst & 127) << 16) | (unsigned int)src;
}

__global__ void place_kernel(const int* __restrict__ rowptr, const unsigned int* __restrict__ stage,
                             unsigned short* __restrict__ csr) {
    __shared__ int cur[128];
    const int b = blockIdx.x;
    const int n0 = b * 128;
    const int t = threadIdx.x;
    if (t < 128) {
        int n = n0 + t;
        cur[t] = (n < N_NODES) ? rowptr[n] : 0;
    }
    __syncthreads();
    int beg = rowptr[n0];
    int nend = n0 + 128; if (nend > N_NODES) nend = N_NODES;
    int end = rowptr[nend];
    for (int i = beg + t; i < end; i += 256) {
        unsigned int v = stage[i];
        int pos = atomicAdd(&cur[v >> 16], 1);
        csr[pos] = (unsigned short)(v & 0xFFFFu);
    }
}

// ------- agg layers 1/2 (HC=64): dual-edge half-wave gather (R9/R7 form) -------
__global__ void agg64_kernel(const int* __restrict__ rowptr, const unsigned short* __restrict__ csr_src,
                             const float* __restrict__ al_s, const float* __restrict__ al_d,
                             const unsigned short* __restrict__ hb, const float* __restrict__ b,
                             float* __restrict__ xn) {
    int node = blockIdx.x * 4 + (threadIdx.x >> 6);   // grid exact: N_NODES % 4 == 0
    int lane = threadIdx.x & 63;
    int half = lane >> 5;
    int hl = lane & 31;
    int c0 = hl * 2;
    int hd = hl >> 3;                                 // head = (2*hl)/16
    float ald = al_d[node * 4 + hd];
    int beg = rowptr[node], end = rowptr[node + 1];
    float denom = 0.f, a0 = 0.f, a1 = 0.f;
    if (half == 0) {   // self loop on half 0
        float w = __expf(lrelu02(al_s[node * 4 + hd] + ald));
        float2 p = bfp2(*(const unsigned int*)(hb + (size_t)node * 64 + c0));
        denom = w; a0 = w * p.x; a1 = w * p.y;
    }
    int j = beg + half;
    for (; j + 6 < end; j += 8) {   // 4 edges per half = 8 edges per wave
        int s0 = csr_src[j], s1 = csr_src[j + 2], s2 = csr_src[j + 4], s3 = csr_src[j + 6];
        unsigned int q0 = *(const unsigned int*)(hb + (size_t)s0 * 64 + c0);
        unsigned int q1 = *(const unsigned int*)(hb + (size_t)s1 * 64 + c0);
        unsigned int q2 = *(const unsigned int*)(hb + (size_t)s2 * 64 + c0);
        unsigned int q3 = *(const unsigned int*)(hb + (size_t)s3 * 64 + c0);
        float w0 = __expf(lrelu02(al_s[s0 * 4 + hd] + ald));
        float w1 = __expf(lrelu02(al_s[s1 * 4 + hd] + ald));
        float w2 = __expf(lrelu02(al_s[s2 * 4 + hd] + ald));
        float w3 = __expf(lrelu02(al_s[s3 * 4 + hd] + ald));
        denom += (w0 + w1) + (w2 + w3);
        float2 p;
        p = bfp2(q0); a0 = fmaf(w0, p.x, a0); a1 = fmaf(w0, p.y, a1);
        p = bfp2(q1); a0 = fmaf(w1, p.x, a0); a1 = fmaf(w1, p.y, a1);
        p = bfp2(q2); a0 = fmaf(w2, p.x, a0); a1 = fmaf(w2, p.y, a1);
        p = bfp2(q3); a0 = fmaf(w3, p.x, a0); a1 = fmaf(w3, p.y, a1);
    }
    for (; j < end; j += 2) {
        int s0 = csr_src[j];
        unsigned int q0 = *(const unsigned int*)(hb + (size_t)s0 * 64 + c0);
        float w0 = __expf(lrelu02(al_s[s0 * 4 + hd] + ald));
        denom += w0;
        float2 p = bfp2(q0);
        a0 = fmaf(w0, p.x, a0); a1 = fmaf(w0, p.y, a1);
    }
    denom += __shfl_xor(denom, 32);
    a0 += __shfl_xor(a0, 32);
    a1 += __shfl_xor(a1, 32);
    if (half == 0) {
        float2 o;
        o.x = elu1(a0 / denom + b[c0]);
        o.y = elu1(a1 / denom + b[c0 + 1]);
        *(float2*)(xn + (size_t)node * 64 + c0) = o;
    }
}

// ------- agg layer 3: fp8 gather (uint/lane = 4 ch, 64 lanes = full 256B row); fused final -------
__global__ void agg240_kernel(const int* __restrict__ rowptr, const unsigned short* __restrict__ csr_src,
                              const float* __restrict__ al_s, const float* __restrict__ al_d,
                              const unsigned int* __restrict__ h8, const float* __restrict__ b3,
                              float* __restrict__ y) {
    __shared__ float sh[4][240];
    int wv_id = threadIdx.x >> 6;
    int node = blockIdx.x * 4 + wv_id;                // grid exact: 12500 blocks
    int lane = threadIdx.x & 63;
    bool act = lane < 60;
    int c0 = lane * 4;                                // 0..252 (pad region for lanes 60-63)
    int hd = act ? (c0 / 40) : 5;                     // clamp for pad lanes
    float ald = al_d[node * 6 + hd];
    int beg = rowptr[node], end = rowptr[node + 1];
    float w = __expf(lrelu02(al_s[node * 6 + hd] + ald));
    float denom = w;
    float4 acc;
    {
        unsigned int q = h8[(size_t)node * 64 + lane];
        v2f lo = __builtin_amdgcn_cvt_pk_f32_fp8((int)q, false);
        v2f hi = __builtin_amdgcn_cvt_pk_f32_fp8((int)q, true);
        acc.x = w * lo.x; acc.y = w * lo.y; acc.z = w * hi.x; acc.w = w * hi.y;
    }
    int j = beg;
    for (; j + 8 <= end; j += 8) {
        int s[8];
#pragma unroll
        for (int u = 0; u < 8; ++u) s[u] = csr_src[j + u];
        unsigned int q[8];
#pragma unroll
        for (int u = 0; u < 8; ++u) q[u] = h8[(size_t)s[u] * 64 + lane];
        float wvv[8];
#pragma unroll
        for (int u = 0; u < 8; ++u) wvv[u] = __expf(lrelu02(al_s[s[u] * 6 + hd] + ald));
#pragma unroll
        for (int u = 0; u < 8; ++u) {
            denom += wvv[u];
            v2f lo = __builtin_amdgcn_cvt_pk_f32_fp8((int)q[u], false);
            v2f hi = __builtin_amdgcn_cvt_pk_f32_fp8((int)q[u], true);
            acc.x = fmaf(wvv[u], lo.x, acc.x); acc.y = fmaf(wvv[u], lo.y, acc.y);
            acc.z = fmaf(wvv[u], hi.x, acc.z); acc.w = fmaf(wvv[u], hi.y, acc.w);
        }
    }
    for (; j < end; ++j) {
        int s0 = csr_src[j];
        unsigned int q0 = h8[(size_t)s0 * 64 + lane];
        float w0 = __expf(lrelu02(al_s[s0 * 6 + hd] + ald));
        denom += w0;
        v2f lo = __builtin_amdgcn_cvt_pk_f32_fp8((int)q0, false);
        v2f hi = __builtin_amdgcn_cvt_pk_f32_fp8((int)q0, true);
        acc.x = fmaf(w0, lo.x, acc.x); acc.y = fmaf(w0, lo.y, acc.y);
        acc.z = fmaf(w0, hi.x, acc.z); acc.w = fmaf(w0, hi.y, acc.w);
    }
    if (act) {
        float r = 1.f / denom;
        float* sp = &sh[wv_id][c0];
        sp[0] = acc.x * r; sp[1] = acc.y * r; sp[2] = acc.z * r; sp[3] = acc.w * r;
    }
    __syncthreads();
    float v;
    if (lane < 40) {
        const float* p = sh[wv_id];
        float s = 0.f;
#pragma unroll
        for (int hh = 0; hh < 6; ++hh) s += p[hh * 40 + lane];
        v = elu1(s * (1.f / 6.f) + b3[lane]);
    } else {
        v = -INFINITY;
    }
    float m = v;
#pragma unroll
    for (int o = 32; o > 0; o >>= 1) m = fmaxf(m, __shfl_xor(m, o));
    float ex = (lane < 40) ? __expf(v - m) : 0.f;
    float ssum = ex;
#pragma unroll
    for (int o = 32; o > 0; o >>= 1) ssum += __shfl_xor(ssum, o);
    if (lane < 40) y[(size_t)node * 40 + lane] = v - m - __logf(ssum);
}

extern "C" void kernel_launch(void* const* d_in, const int* in_sizes, int n_in,
                              void* d_out, int out_size, void* d_ws, size_t ws_size,
                              hipStream_t stream) {
    const float* x   = (const float*)d_in[0];
    const int*   ei  = (const int*)d_in[1];   // [2, E]
    const float* W1  = (const float*)d_in[2];
    const float* a1s = (const float*)d_in[3];
    const float* a1d = (const float*)d_in[4];
    const float* b1  = (const float*)d_in[5];
    const float* W2  = (const float*)d_in[6];
    const float* a2s = (const float*)d_in[7];
    const float* a2d = (const float*)d_in[8];
    const float* b2  = (const float*)d_in[9];
    const float* W3  = (const float*)d_in[10];
    const float* a3s = (const float*)d_in[11];
    const float* a3d = (const float*)d_in[12];
    const float* b3  = (const float*)d_in[13];
    float* y = (float*)d_out;

    float* ws = (float*)d_ws;
    unsigned short* h_bf = (unsigned short*)ws;               // 3.2M ushort (layers 1/2, node-major)
    float* x_buf   = ws + 1600000;                            // 3,200,000 floats
    float* al_s    = ws + 4800000;                            //   300,000
    float* al_d    = ws + 5100000;                            //   300,000
    unsigned int* h8 = (unsigned int*)(ws + 5400000);         // 3.2M uints (layer-3 fp8, 256B rows)
    int*   deg     = (int*)(ws + 8600000);                    //    50,000
    int*   rowptr  = (int*)(ws + 8650000);                    //    50,001
    unsigned short* csr_src = (unsigned short*)(ws + 8700008);  // 1.6M ushort
    unsigned int* stage = (unsigned int*)(ws + 9500008);      // 1.6M uint
    int* bcur = (int*)(ws + 11100008);                        // NB*16 ints
    // total ~11.11M floats = 44.4 MB

    // ---- CSR build via bucketed counting sort (once; shared by all 3 layers) ----
    hipMemsetAsync(deg, 0, N_NODES * sizeof(int), stream);
    deg_kernel<<<(N_EDGES + 255) / 256, 256, 0, stream>>>(ei, deg);
    scan_kernel<<<1, 1024, 0, stream>>>(deg, rowptr);
    initcur_kernel<<<(NB + 255) / 256, 256, 0, stream>>>(rowptr, bcur);
    bucket_kernel<<<(N_EDGES + 255) / 256, 256, 0, stream>>>(ei, bcur, stage);
    place_kernel<<<NB, 256, 0, stream>>>(rowptr, stage, csr_src);

    const int agg_grid = N_NODES / 4;              // 12500, exact
    const int gemm_gx = (N_NODES + 31) / 32;
    dim3 gblk(64, 4);

    // ---- layer 1: 128 -> (4,16) concat ----
    gemm_al_kernel<128><<<gemm_gx, gblk, 0, stream>>>(x, W1, a1s, a1d, h_bf, al_s, al_d);
    agg64_kernel<<<agg_grid, 256, 0, stream>>>(rowptr, csr_src, al_s, al_d, h_bf, b1, x_buf);

    // ---- layer 2: 64 -> (4,16) concat ----
    gemm_al_kernel<64><<<gemm_gx, gblk, 0, stream>>>(x_buf, W2, a2s, a2d, h_bf, al_s, al_d);
    agg64_kernel<<<agg_grid, 256, 0, stream>>>(rowptr, csr_src, al_s, al_d, h_bf, b2, x_buf);

    // ---- layer 3: 64 -> (6,40) mean; fp8 h ----
    gemm240_kernel<<<gemm_gx, gblk, 0, stream>>>(x_buf, W3, a3s, a3d, h8, al_s, al_d);
    agg240_kernel<<<agg_grid, 256, 0, stream>>>(rowptr, csr_src, al_s, al_d, h8, b3, y);
}

// Round 13
// 579.839 us; speedup vs baseline: 1.6640x; 1.1581x over previous
//
#include <hip/hip_runtime.h>
#include <math.h>

#define N_NODES 50000
#define N_EDGES 1600000
#define NB      391          // ceil(50000/128) buckets of 128 nodes

typedef __attribute__((ext_vector_type(2))) float v2f;

__device__ __forceinline__ float lrelu02(float x) { return x > 0.f ? x : 0.2f * x; }
__device__ __forceinline__ float elu1(float x)    { return x > 0.f ? x : __expf(x) - 1.f; }

// bf16 helpers (RNE pack)
__device__ __forceinline__ unsigned short f2bf(float f) {
    unsigned int u = __float_as_uint(f);
    return (unsigned short)((u + 0x7fffu + ((u >> 16) & 1u)) >> 16);
}
__device__ __forceinline__ float2 bfp2(unsigned int u) {
    float2 r;
    r.x = __uint_as_float(u << 16);
    r.y = __uint_as_float(u & 0xffff0000u);
    return r;
}

// ------- GEMM layers 1/2 (FOUT=64) fused with attention logits -------
template<int FIN>
__global__ void gemm_al_kernel(const float* __restrict__ x, const float* __restrict__ W,
                               const float* __restrict__ a_s, const float* __restrict__ a_d,
                               unsigned short* __restrict__ h,
                               float* __restrict__ al_s, float* __restrict__ al_d) {
    __shared__ float Wl[FIN][64];
    __shared__ unsigned short ot[32][66];   // +2 pad
    const int tx = threadIdx.x, ty = threadIdx.y;
    const int tid = ty * 64 + tx;
    for (int i = tid; i < FIN * 64; i += 256) {
        int k = i >> 6, f = i & 63;
        Wl[k][f] = W[(size_t)k * 64 + f];
    }
    __syncthreads();
    const int n0b = blockIdx.x * 32;
    const int n0 = n0b + ty * 8;
    float acc[8] = {0.f, 0.f, 0.f, 0.f, 0.f, 0.f, 0.f, 0.f};
    if (n0 + 8 <= N_NODES) {
        for (int k = 0; k < FIN; k += 4) {
            float4 xv[8];
#pragma unroll
            for (int i = 0; i < 8; ++i)
                xv[i] = *(const float4*)(x + (size_t)(n0 + i) * FIN + k);
#pragma unroll
            for (int kk = 0; kk < 4; ++kk) {
                float w = Wl[k + kk][tx];
#pragma unroll
                for (int i = 0; i < 8; ++i) {
                    float xs = (kk == 0) ? xv[i].x : (kk == 1) ? xv[i].y : (kk == 2) ? xv[i].z : xv[i].w;
                    acc[i] = fmaf(xs, w, acc[i]);
                }
            }
        }
    } else {
        for (int i = 0; i < 8; ++i) {
            if (n0 + i >= N_NODES) break;
            const float* xr = x + (size_t)(n0 + i) * FIN;
            float a = 0.f;
            for (int k = 0; k < FIN; ++k) a = fmaf(xr[k], Wl[k][tx], a);
            acc[i] = a;
        }
    }
#pragma unroll
    for (int i = 0; i < 8; ++i) ot[ty * 8 + i][tx] = f2bf(acc[i]);
    __syncthreads();
    int vrows = N_NODES - n0b; if (vrows > 32) vrows = 32;
    {   // node-major coalesced writeout
        unsigned int* ph = (unsigned int*)(h + (size_t)n0b * 64);
        for (int i = tid; i < vrows * 32; i += 256) {
            int row = i >> 5, col = i & 31;
            ph[i] = *(const unsigned int*)&ot[row][col * 2];
        }
    }
    if (tid < 128) {
        int node = tid >> 2, hd = tid & 3;
        if (node < vrows) {
            const float* as = a_s + hd * 16;
            const float* ad = a_d + hd * 16;
            float s1 = 0.f, s2 = 0.f;
#pragma unroll
            for (int c = 0; c < 16; c += 2) {
                unsigned int q = *(const unsigned int*)&ot[node][hd * 16 + c];
                float2 p = bfp2(q);
                s1 = fmaf(p.x, as[c], s1);     s2 = fmaf(p.x, ad[c], s2);
                s1 = fmaf(p.y, as[c + 1], s1); s2 = fmaf(p.y, ad[c + 1], s2);
            }
            al_s[(n0b + node) * 4 + hd] = s1;
            al_d[(n0b + node) * 4 + hd] = s2;
        }
    }
}

// ------- L3 GEMM: fused al3; h written as FP8 e4m3, 256B-aligned rows (64 uints) -------
__global__ void gemm240_kernel(const float* __restrict__ x, const float* __restrict__ W,
                               const float* __restrict__ a_s, const float* __restrict__ a_d,
                               unsigned int* __restrict__ h8,
                               float* __restrict__ al_s, float* __restrict__ al_d) {
    __shared__ float Wl[64][240];           // 61440 B
    __shared__ unsigned short ot[32][240];  // 15360 B
    const int tx = threadIdx.x, ty = threadIdx.y;
    const int tid = ty * 64 + tx;
    {
        const float4* W4 = (const float4*)W;
        float4* Wl4 = (float4*)&Wl[0][0];
        for (int i = tid; i < 64 * 240 / 4; i += 256) Wl4[i] = W4[i];
    }
    __syncthreads();
    const int n0b = blockIdx.x * 32;
    const int n0 = n0b + ty * 8;
    float acc[4][8];
#pragma unroll
    for (int g = 0; g < 4; ++g)
#pragma unroll
        for (int i = 0; i < 8; ++i) acc[g][i] = 0.f;
    const int tx3 = (tx < 48) ? (192 + tx) : 0;
    if (n0 + 8 <= N_NODES) {
        for (int k = 0; k < 64; k += 4) {
            float4 xv[8];
#pragma unroll
            for (int i = 0; i < 8; ++i)
                xv[i] = *(const float4*)(x + (size_t)(n0 + i) * 64 + k);
#pragma unroll
            for (int kk = 0; kk < 4; ++kk) {
                float w0 = Wl[k + kk][tx];
                float w1 = Wl[k + kk][64 + tx];
                float w2 = Wl[k + kk][128 + tx];
                float w3 = Wl[k + kk][tx3];
#pragma unroll
                for (int i = 0; i < 8; ++i) {
                    float xs = (kk == 0) ? xv[i].x : (kk == 1) ? xv[i].y : (kk == 2) ? xv[i].z : xv[i].w;
                    acc[0][i] = fmaf(xs, w0, acc[0][i]);
                    acc[1][i] = fmaf(xs, w1, acc[1][i]);
                    acc[2][i] = fmaf(xs, w2, acc[2][i]);
                    acc[3][i] = fmaf(xs, w3, acc[3][i]);
                }
            }
        }
    } else {
        for (int i = 0; i < 8; ++i) {
            if (n0 + i >= N_NODES) break;
            const float* xr = x + (size_t)(n0 + i) * 64;
            for (int k = 0; k < 64; ++k) {
                float xs = xr[k];
                acc[0][i] = fmaf(xs, Wl[k][tx], acc[0][i]);
                acc[1][i] = fmaf(xs, Wl[k][64 + tx], acc[1][i]);
                acc[2][i] = fmaf(xs, Wl[k][128 + tx], acc[2][i]);
                acc[3][i] = fmaf(xs, Wl[k][tx3], acc[3][i]);
            }
        }
    }
#pragma unroll
    for (int i = 0; i < 8; ++i) {
        ot[ty * 8 + i][tx] = f2bf(acc[0][i]);
        ot[ty * 8 + i][64 + tx] = f2bf(acc[1][i]);
        ot[ty * 8 + i][128 + tx] = f2bf(acc[2][i]);
        if (tx < 48) ot[ty * 8 + i][192 + tx] = f2bf(acc[3][i]);
    }
    __syncthreads();
    int vrows = N_NODES - n0b; if (vrows > 32) vrows = 32;
    {   // fp8 writeout: 64 uints per node row (last 4 are zero pad)
        for (int i = tid; i < vrows * 64; i += 256) {
            int row = i >> 6, c = i & 63;
            unsigned int packed = 0;
            if (c < 60) {
                uint2 q = *(const uint2*)&ot[row][c * 4];
                float2 p0 = bfp2(q.x), p1 = bfp2(q.y);
                int lo = __builtin_amdgcn_cvt_pk_fp8_f32(p0.x, p0.y, 0, false);
                packed = (unsigned int)__builtin_amdgcn_cvt_pk_fp8_f32(p1.x, p1.y, lo, true);
            }
            h8[(size_t)(n0b + row) * 64 + c] = packed;
        }
    }
    if (tid < 192) {
        int node = tid / 6, hd = tid % 6;
        if (node < vrows) {
            const unsigned short* r = &ot[node][hd * 40];
            const float* as = a_s + hd * 40;
            const float* ad = a_d + hd * 40;
            float s1 = 0.f, s2 = 0.f;
            for (int c = 0; c < 40; c += 2) {
                unsigned int q = *(const unsigned int*)(r + c);
                float2 p = bfp2(q);
                s1 = fmaf(p.x, as[c], s1);     s2 = fmaf(p.x, ad[c], s2);
                s1 = fmaf(p.y, as[c + 1], s1); s2 = fmaf(p.y, ad[c + 1], s2);
            }
            al_s[(n0b + node) * 6 + hd] = s1;
            al_d[(n0b + node) * 6 + hd] = s2;
        }
    }
}

// ---------------- CSR build (hierarchical, no serial 50k scan) ----------------
__global__ void deg_kernel(const int* __restrict__ ei, int* __restrict__ deg) {
    int e = blockIdx.x * 256 + threadIdx.x;
    if (e >= N_EDGES) return;
    atomicAdd(&deg[ei[N_EDGES + e]], 1);
}

// per-bucket degree sums: one block of 128 per bucket
__global__ void bsum_kernel(const int* __restrict__ deg, int* __restrict__ bcnt) {
    __shared__ int wsum[2];
    int b = blockIdx.x, t = threadIdx.x;
    int n = b * 128 + t;
    int v = (n < N_NODES) ? deg[n] : 0;
#pragma unroll
    for (int off = 1; off < 64; off <<= 1) v += __shfl_xor(v, off);
    if ((t & 63) == 0) wsum[t >> 6] = v;
    __syncthreads();
    if (t == 0) bcnt[b] = wsum[0] + wsum[1];
}

// scan the 391 bucket counts; init bucket bases + padded cursors
__global__ void scan391_kernel(const int* __restrict__ bcnt, int* __restrict__ bbase,
                               int* __restrict__ bcur) {
    __shared__ int wtot[8];
    int b = threadIdx.x;              // 512 threads, 8 waves
    int lane = b & 63, w = b >> 6;
    int v = (b < NB) ? bcnt[b] : 0;
    int sc = v;
#pragma unroll
    for (int off = 1; off < 64; off <<= 1) {
        int u = __shfl_up(sc, off);
        if (lane >= off) sc += u;
    }
    if (lane == 63) wtot[w] = sc;
    __syncthreads();
    int add = 0;
    for (int k = 0; k < w; ++k) add += wtot[k];
    int excl = sc - v + add;
    if (b < NB) { bbase[b] = excl; bcur[b * 16] = excl; }
    if (b == 0) bbase[NB] = N_EDGES;
}

// pass A: append (dst_low, src) into per-bucket staging region
__global__ void bucket_kernel(const int* __restrict__ ei, int* __restrict__ bcur,
                              unsigned int* __restrict__ stage) {
    int e = blockIdx.x * 256 + threadIdx.x;
    if (e >= N_EDGES) return;
    int src = ei[e], dst = ei[N_EDGES + e];
    int pos = atomicAdd(&bcur[(dst >> 7) * 16], 1);
    stage[pos] = ((unsigned int)(dst & 127) << 16) | (unsigned int)src;
}

// pass B: one block per bucket; LDS scan of its 128 degs -> rowptr + cursors; then place
__global__ void place_kernel(const int* __restrict__ deg, const int* __restrict__ bbase,
                             const unsigned int* __restrict__ stage,
                             int* __restrict__ rowptr, unsigned short* __restrict__ csr) {
    __shared__ int cur[128];
    __shared__ int wt[2];
    const int b = blockIdx.x;
    const int n0 = b * 128;
    const int t = threadIdx.x;
    const int base = bbase[b];
    const int endp = bbase[b + 1];
    int v = 0, sc = 0;
    if (t < 128) {
        int n = n0 + t;
        v = (n < N_NODES) ? deg[n] : 0;
        int lane = t & 63, w = t >> 6;
        sc = v;
#pragma unroll
        for (int off = 1; off < 64; off <<= 1) {
            int u = __shfl_up(sc, off);
            if (lane >= off) sc += u;
        }
        if (lane == 63) wt[w] = sc;
    }
    __syncthreads();
    if (t < 128) {
        int add = (t >= 64) ? wt[0] : 0;
        int excl = sc - v + add;
        int n = n0 + t;
        if (n <= N_NODES) rowptr[n] = base + excl;   // rowptr[N] emitted by last bucket
        cur[t] = base + excl;
    }
    __syncthreads();
    for (int i = base + t; i < endp; i += 256) {
        unsigned int e = stage[i];
        int pos = atomicAdd(&cur[e >> 16], 1);
        csr[pos] = (unsigned short)(e & 0xFFFFu);
    }
}

// ------- agg layers 1/2 (HC=64): dual-edge half-wave gather -------
__global__ void agg64_kernel(const int* __restrict__ rowptr, const unsigned short* __restrict__ csr_src,
                             const float* __restrict__ al_s, const float* __restrict__ al_d,
                             const unsigned short* __restrict__ hb, const float* __restrict__ b,
                             float* __restrict__ xn) {
    int node = blockIdx.x * 4 + (threadIdx.x >> 6);   // grid exact: N_NODES % 4 == 0
    int lane = threadIdx.x & 63;
    int half = lane >> 5;
    int hl = lane & 31;
    int c0 = hl * 2;
    int hd = hl >> 3;                                 // head = (2*hl)/16
    float ald = al_d[node * 4 + hd];
    int beg = rowptr[node], end = rowptr[node + 1];
    float denom = 0.f, a0 = 0.f, a1 = 0.f;
    if (half == 0) {   // self loop on half 0
        float w = __expf(lrelu02(al_s[node * 4 + hd] + ald));
        float2 p = bfp2(*(const unsigned int*)(hb + (size_t)node * 64 + c0));
        denom = w; a0 = w * p.x; a1 = w * p.y;
    }
    int j = beg + half;
    for (; j + 6 < end; j += 8) {   // 4 edges per half = 8 edges per wave
        int s0 = csr_src[j], s1 = csr_src[j + 2], s2 = csr_src[j + 4], s3 = csr_src[j + 6];
        unsigned int q0 = *(const unsigned int*)(hb + (size_t)s0 * 64 + c0);
        unsigned int q1 = *(const unsigned int*)(hb + (size_t)s1 * 64 + c0);
        unsigned int q2 = *(const unsigned int*)(hb + (size_t)s2 * 64 + c0);
        unsigned int q3 = *(const unsigned int*)(hb + (size_t)s3 * 64 + c0);
        float w0 = __expf(lrelu02(al_s[s0 * 4 + hd] + ald));
        float w1 = __expf(lrelu02(al_s[s1 * 4 + hd] + ald));
        float w2 = __expf(lrelu02(al_s[s2 * 4 + hd] + ald));
        float w3 = __expf(lrelu02(al_s[s3 * 4 + hd] + ald));
        denom += (w0 + w1) + (w2 + w3);
        float2 p;
        p = bfp2(q0); a0 = fmaf(w0, p.x, a0); a1 = fmaf(w0, p.y, a1);
        p = bfp2(q1); a0 = fmaf(w1, p.x, a0); a1 = fmaf(w1, p.y, a1);
        p = bfp2(q2); a0 = fmaf(w2, p.x, a0); a1 = fmaf(w2, p.y, a1);
        p = bfp2(q3); a0 = fmaf(w3, p.x, a0); a1 = fmaf(w3, p.y, a1);
    }
    for (; j < end; j += 2) {
        int s0 = csr_src[j];
        unsigned int q0 = *(const unsigned int*)(hb + (size_t)s0 * 64 + c0);
        float w0 = __expf(lrelu02(al_s[s0 * 4 + hd] + ald));
        denom += w0;
        float2 p = bfp2(q0);
        a0 = fmaf(w0, p.x, a0); a1 = fmaf(w0, p.y, a1);
    }
    denom += __shfl_xor(denom, 32);
    a0 += __shfl_xor(a0, 32);
    a1 += __shfl_xor(a1, 32);
    if (half == 0) {
        float2 o;
        o.x = elu1(a0 / denom + b[c0]);
        o.y = elu1(a1 / denom + b[c0 + 1]);
        *(float2*)(xn + (size_t)node * 64 + c0) = o;
    }
}

// ------- agg layer 3: fp8 gather (uint/lane = 4 ch, 64 lanes = full 256B row); fused final -------
__global__ void agg240_kernel(const int* __restrict__ rowptr, const unsigned short* __restrict__ csr_src,
                              const float* __restrict__ al_s, const float* __restrict__ al_d,
                              const unsigned int* __restrict__ h8, const float* __restrict__ b3,
                              float* __restrict__ y) {
    __shared__ float sh[4][240];
    int wv_id = threadIdx.x >> 6;
    int node = blockIdx.x * 4 + wv_id;                // grid exact: 12500 blocks
    int lane = threadIdx.x & 63;
    bool act = lane < 60;
    int c0 = lane * 4;                                // 0..252 (pad region for lanes 60-63)
    int hd = act ? (c0 / 40) : 5;                     // clamp for pad lanes
    float ald = al_d[node * 6 + hd];
    int beg = rowptr[node], end = rowptr[node + 1];
    float w = __expf(lrelu02(al_s[node * 6 + hd] + ald));
    float denom = w;
    float4 acc;
    {
        unsigned int q = h8[(size_t)node * 64 + lane];
        v2f lo = __builtin_amdgcn_cvt_pk_f32_fp8((int)q, false);
        v2f hi = __builtin_amdgcn_cvt_pk_f32_fp8((int)q, true);
        acc.x = w * lo.x; acc.y = w * lo.y; acc.z = w * hi.x; acc.w = w * hi.y;
    }
    int j = beg;
    for (; j + 8 <= end; j += 8) {
        int s[8];
#pragma unroll
        for (int u = 0; u < 8; ++u) s[u] = csr_src[j + u];
        unsigned int q[8];
#pragma unroll
        for (int u = 0; u < 8; ++u) q[u] = h8[(size_t)s[u] * 64 + lane];
        float wvv[8];
#pragma unroll
        for (int u = 0; u < 8; ++u) wvv[u] = __expf(lrelu02(al_s[s[u] * 6 + hd] + ald));
#pragma unroll
        for (int u = 0; u < 8; ++u) {
            denom += wvv[u];
            v2f lo = __builtin_amdgcn_cvt_pk_f32_fp8((int)q[u], false);
            v2f hi = __builtin_amdgcn_cvt_pk_f32_fp8((int)q[u], true);
            acc.x = fmaf(wvv[u], lo.x, acc.x); acc.y = fmaf(wvv[u], lo.y, acc.y);
            acc.z = fmaf(wvv[u], hi.x, acc.z); acc.w = fmaf(wvv[u], hi.y, acc.w);
        }
    }
    for (; j < end; ++j) {
        int s0 = csr_src[j];
        unsigned int q0 = h8[(size_t)s0 * 64 + lane];
        float w0 = __expf(lrelu02(al_s[s0 * 6 + hd] + ald));
        denom += w0;
        v2f lo = __builtin_amdgcn_cvt_pk_f32_fp8((int)q0, false);
        v2f hi = __builtin_amdgcn_cvt_pk_f32_fp8((int)q0, true);
        acc.x = fmaf(w0, lo.x, acc.x); acc.y = fmaf(w0, lo.y, acc.y);
        acc.z = fmaf(w0, hi.x, acc.z); acc.w = fmaf(w0, hi.y, acc.w);
    }
    if (act) {
        float r = 1.f / denom;
        float* sp = &sh[wv_id][c0];
        sp[0] = acc.x * r; sp[1] = acc.y * r; sp[2] = acc.z * r; sp[3] = acc.w * r;
    }
    __syncthreads();
    float v;
    if (lane < 40) {
        const float* p = sh[wv_id];
        float s = 0.f;
#pragma unroll
        for (int hh = 0; hh < 6; ++hh) s += p[hh * 40 + lane];
        v = elu1(s * (1.f / 6.f) + b3[lane]);
    } else {
        v = -INFINITY;
    }
    float m = v;
#pragma unroll
    for (int o = 32; o > 0; o >>= 1) m = fmaxf(m, __shfl_xor(m, o));
    float ex = (lane < 40) ? __expf(v - m) : 0.f;
    float ssum = ex;
#pragma unroll
    for (int o = 32; o > 0; o >>= 1) ssum += __shfl_xor(ssum, o);
    if (lane < 40) y[(size_t)node * 40 + lane] = v - m - __logf(ssum);
}

extern "C" void kernel_launch(void* const* d_in, const int* in_sizes, int n_in,
                              void* d_out, int out_size, void* d_ws, size_t ws_size,
                              hipStream_t stream) {
    const float* x   = (const float*)d_in[0];
    const int*   ei  = (const int*)d_in[1];   // [2, E]
    const float* W1  = (const float*)d_in[2];
    const float* a1s = (const float*)d_in[3];
    const float* a1d = (const float*)d_in[4];
    const float* b1  = (const float*)d_in[5];
    const float* W2  = (const float*)d_in[6];
    const float* a2s = (const float*)d_in[7];
    const float* a2d = (const float*)d_in[8];
    const float* b2  = (const float*)d_in[9];
    const float* W3  = (const float*)d_in[10];
    const float* a3s = (const float*)d_in[11];
    const float* a3d = (const float*)d_in[12];
    const float* b3  = (const float*)d_in[13];
    float* y = (float*)d_out;

    float* ws = (float*)d_ws;
    unsigned short* h_bf = (unsigned short*)ws;               // 3.2M ushort (layers 1/2)
    float* x_buf   = ws + 1600000;                            // 3,200,000 floats
    float* al_s    = ws + 4800000;                            //   300,000
    float* al_d    = ws + 5100000;                            //   300,000
    unsigned int* h8 = (unsigned int*)(ws + 5400000);         // 3.2M uints (layer-3 fp8, 256B rows)
    int*   deg     = (int*)(ws + 8600000);                    //    50,000
    int*   rowptr  = (int*)(ws + 8650000);                    //    50,001
    unsigned short* csr_src = (unsigned short*)(ws + 8700008);  // 1.6M ushort
    unsigned int* stage = (unsigned int*)(ws + 9500008);      // 1.6M uint
    int* bcur = (int*)(ws + 11100008);                        // NB*16 ints
    int* bcnt = (int*)(ws + 11106264);                        // NB ints
    int* bbase = (int*)(ws + 11106656);                       // NB+1 ints
    // total ~11.11M floats = 44.4 MB

    // ---- CSR build: hierarchical counting sort (no serial 50k scan) ----
    hipMemsetAsync(deg, 0, N_NODES * sizeof(int), stream);
    deg_kernel<<<(N_EDGES + 255) / 256, 256, 0, stream>>>(ei, deg);
    bsum_kernel<<<NB, 128, 0, stream>>>(deg, bcnt);
    scan391_kernel<<<1, 512, 0, stream>>>(bcnt, bbase, bcur);
    bucket_kernel<<<(N_EDGES + 255) / 256, 256, 0, stream>>>(ei, bcur, stage);
    place_kernel<<<NB, 256, 0, stream>>>(deg, bbase, stage, rowptr, csr_src);

    const int agg_grid = N_NODES / 4;              // 12500, exact
    const int gemm_gx = (N_NODES + 31) / 32;
    dim3 gblk(64, 4);

    // ---- layer 1: 128 -> (4,16) concat ----
    gemm_al_kernel<128><<<gemm_gx, gblk, 0, stream>>>(x, W1, a1s, a1d, h_bf, al_s, al_d);
    agg64_kernel<<<agg_grid, 256, 0, stream>>>(rowptr, csr_src, al_s, al_d, h_bf, b1, x_buf);

    // ---- layer 2: 64 -> (4,16) concat ----
    gemm_al_kernel<64><<<gemm_gx, gblk, 0, stream>>>(x_buf, W2, a2s, a2d, h_bf, al_s, al_d);
    agg64_kernel<<<agg_grid, 256, 0, stream>>>(rowptr, csr_src, al_s, al_d, h_bf, b2, x_buf);

    // ---- layer 3: 64 -> (6,40) mean; fp8 h ----
    gemm240_kernel<<<gemm_gx, gblk, 0, stream>>>(x_buf, W3, a3s, a3d, h8, al_s, al_d);
    agg240_kernel<<<agg_grid, 256, 0, stream>>>(rowptr, csr_src, al_s, al_d, h8, b3, y);
}

// Round 14
// 569.363 us; speedup vs baseline: 1.6946x; 1.0184x over previous
//
#include <hip/hip_runtime.h>
#include <math.h>

#define N_NODES 50000
#define N_EDGES 1600000
#define NB      391          // ceil(50000/128) buckets of 128 nodes

typedef __attribute__((ext_vector_type(2))) float v2f;

__device__ __forceinline__ float lrelu02(float x) { return x > 0.f ? x : 0.2f * x; }
__device__ __forceinline__ float elu1(float x)    { return x > 0.f ? x : __expf(x) - 1.f; }

// bf16 helpers (RNE pack)
__device__ __forceinline__ unsigned short f2bf(float f) {
    unsigned int u = __float_as_uint(f);
    return (unsigned short)((u + 0x7fffu + ((u >> 16) & 1u)) >> 16);
}
__device__ __forceinline__ float bf2f(unsigned short s) {
    return __uint_as_float((unsigned int)s << 16);
}
__device__ __forceinline__ float2 bfp2(unsigned int u) {
    float2 r;
    r.x = __uint_as_float(u << 16);
    r.y = __uint_as_float(u & 0xffff0000u);
    return r;
}

// ------- GEMM layers 1/2 (FOUT=64) fused with attention logits -------
// W staged in LDS as bf16: FIN=128 -> 20.6 KB total LDS -> ~7 blocks/CU (was 4).
template<int FIN>
__global__ void gemm_al_kernel(const float* __restrict__ x, const float* __restrict__ W,
                               const float* __restrict__ a_s, const float* __restrict__ a_d,
                               unsigned short* __restrict__ h,
                               float* __restrict__ al_s, float* __restrict__ al_d) {
    __shared__ unsigned short Wl[FIN][64];  // bf16
    __shared__ unsigned short ot[32][66];   // +2 pad
    const int tx = threadIdx.x, ty = threadIdx.y;
    const int tid = ty * 64 + tx;
    for (int i = tid; i < FIN * 64; i += 256) {
        int k = i >> 6, f = i & 63;
        Wl[k][f] = f2bf(W[(size_t)k * 64 + f]);
    }
    __syncthreads();
    const int n0b = blockIdx.x * 32;
    const int n0 = n0b + ty * 8;
    float acc[8] = {0.f, 0.f, 0.f, 0.f, 0.f, 0.f, 0.f, 0.f};
    if (n0 + 8 <= N_NODES) {
        for (int k = 0; k < FIN; k += 4) {
            float4 xv[8];
#pragma unroll
            for (int i = 0; i < 8; ++i)
                xv[i] = *(const float4*)(x + (size_t)(n0 + i) * FIN + k);
#pragma unroll
            for (int kk = 0; kk < 4; ++kk) {
                float w = bf2f(Wl[k + kk][tx]);
#pragma unroll
                for (int i = 0; i < 8; ++i) {
                    float xs = (kk == 0) ? xv[i].x : (kk == 1) ? xv[i].y : (kk == 2) ? xv[i].z : xv[i].w;
                    acc[i] = fmaf(xs, w, acc[i]);
                }
            }
        }
    } else {
        for (int i = 0; i < 8; ++i) {
            if (n0 + i >= N_NODES) break;
            const float* xr = x + (size_t)(n0 + i) * FIN;
            float a = 0.f;
            for (int k = 0; k < FIN; ++k) a = fmaf(xr[k], bf2f(Wl[k][tx]), a);
            acc[i] = a;
        }
    }
#pragma unroll
    for (int i = 0; i < 8; ++i) ot[ty * 8 + i][tx] = f2bf(acc[i]);
    __syncthreads();
    int vrows = N_NODES - n0b; if (vrows > 32) vrows = 32;
    {   // node-major coalesced writeout
        unsigned int* ph = (unsigned int*)(h + (size_t)n0b * 64);
        for (int i = tid; i < vrows * 32; i += 256) {
            int row = i >> 5, col = i & 31;
            ph[i] = *(const unsigned int*)&ot[row][col * 2];
        }
    }
    if (tid < 128) {
        int node = tid >> 2, hd = tid & 3;
        if (node < vrows) {
            const float* as = a_s + hd * 16;
            const float* ad = a_d + hd * 16;
            float s1 = 0.f, s2 = 0.f;
#pragma unroll
            for (int c = 0; c < 16; c += 2) {
                unsigned int q = *(const unsigned int*)&ot[node][hd * 16 + c];
                float2 p = bfp2(q);
                s1 = fmaf(p.x, as[c], s1);     s2 = fmaf(p.x, ad[c], s2);
                s1 = fmaf(p.y, as[c + 1], s1); s2 = fmaf(p.y, ad[c + 1], s2);
            }
            al_s[(n0b + node) * 4 + hd] = s1;
            al_d[(n0b + node) * 4 + hd] = s2;
        }
    }
}

// ------- L3 GEMM: fused al3; W in LDS bf16 (30.7 KB); h written FP8 e4m3, 256B rows -------
__global__ void gemm240_kernel(const float* __restrict__ x, const float* __restrict__ W,
                               const float* __restrict__ a_s, const float* __restrict__ a_d,
                               unsigned int* __restrict__ h8,
                               float* __restrict__ al_s, float* __restrict__ al_d) {
    __shared__ unsigned short Wl[64][240];  // bf16, 30720 B
    __shared__ unsigned short ot[32][240];  // 15360 B
    const int tx = threadIdx.x, ty = threadIdx.y;
    const int tid = ty * 64 + tx;
    for (int i = tid; i < 64 * 240; i += 256) Wl[0][i] = f2bf(W[i]);
    __syncthreads();
    const int n0b = blockIdx.x * 32;
    const int n0 = n0b + ty * 8;
    float acc[4][8];
#pragma unroll
    for (int g = 0; g < 4; ++g)
#pragma unroll
        for (int i = 0; i < 8; ++i) acc[g][i] = 0.f;
    const int tx3 = (tx < 48) ? (192 + tx) : 0;
    if (n0 + 8 <= N_NODES) {
        for (int k = 0; k < 64; k += 4) {
            float4 xv[8];
#pragma unroll
            for (int i = 0; i < 8; ++i)
                xv[i] = *(const float4*)(x + (size_t)(n0 + i) * 64 + k);
#pragma unroll
            for (int kk = 0; kk < 4; ++kk) {
                float w0 = bf2f(Wl[k + kk][tx]);
                float w1 = bf2f(Wl[k + kk][64 + tx]);
                float w2 = bf2f(Wl[k + kk][128 + tx]);
                float w3 = bf2f(Wl[k + kk][tx3]);
#pragma unroll
                for (int i = 0; i < 8; ++i) {
                    float xs = (kk == 0) ? xv[i].x : (kk == 1) ? xv[i].y : (kk == 2) ? xv[i].z : xv[i].w;
                    acc[0][i] = fmaf(xs, w0, acc[0][i]);
                    acc[1][i] = fmaf(xs, w1, acc[1][i]);
                    acc[2][i] = fmaf(xs, w2, acc[2][i]);
                    acc[3][i] = fmaf(xs, w3, acc[3][i]);
                }
            }
        }
    } else {
        for (int i = 0; i < 8; ++i) {
            if (n0 + i >= N_NODES) break;
            const float* xr = x + (size_t)(n0 + i) * 64;
            for (int k = 0; k < 64; ++k) {
                float xs = xr[k];
                acc[0][i] = fmaf(xs, bf2f(Wl[k][tx]), acc[0][i]);
                acc[1][i] = fmaf(xs, bf2f(Wl[k][64 + tx]), acc[1][i]);
                acc[2][i] = fmaf(xs, bf2f(Wl[k][128 + tx]), acc[2][i]);
                acc[3][i] = fmaf(xs, bf2f(Wl[k][tx3]), acc[3][i]);
            }
        }
    }
#pragma unroll
    for (int i = 0; i < 8; ++i) {
        ot[ty * 8 + i][tx] = f2bf(acc[0][i]);
        ot[ty * 8 + i][64 + tx] = f2bf(acc[1][i]);
        ot[ty * 8 + i][128 + tx] = f2bf(acc[2][i]);
        if (tx < 48) ot[ty * 8 + i][192 + tx] = f2bf(acc[3][i]);
    }
    __syncthreads();
    int vrows = N_NODES - n0b; if (vrows > 32) vrows = 32;
    {   // fp8 writeout: 64 uints per node row (last 4 are zero pad)
        for (int i = tid; i < vrows * 64; i += 256) {
            int row = i >> 6, c = i & 63;
            unsigned int packed = 0;
            if (c < 60) {
                uint2 q = *(const uint2*)&ot[row][c * 4];
                float2 p0 = bfp2(q.x), p1 = bfp2(q.y);
                int lo = __builtin_amdgcn_cvt_pk_fp8_f32(p0.x, p0.y, 0, false);
                packed = (unsigned int)__builtin_amdgcn_cvt_pk_fp8_f32(p1.x, p1.y, lo, true);
            }
            h8[(size_t)(n0b + row) * 64 + c] = packed;
        }
    }
    if (tid < 192) {
        int node = tid / 6, hd = tid % 6;
        if (node < vrows) {
            const unsigned short* r = &ot[node][hd * 40];
            const float* as = a_s + hd * 40;
            const float* ad = a_d + hd * 40;
            float s1 = 0.f, s2 = 0.f;
            for (int c = 0; c < 40; c += 2) {
                unsigned int q = *(const unsigned int*)(r + c);
                float2 p = bfp2(q);
                s1 = fmaf(p.x, as[c], s1);     s2 = fmaf(p.x, ad[c], s2);
                s1 = fmaf(p.y, as[c + 1], s1); s2 = fmaf(p.y, ad[c + 1], s2);
            }
            al_s[(n0b + node) * 6 + hd] = s1;
            al_d[(n0b + node) * 6 + hd] = s2;
        }
    }
}

// ---------------- CSR build (hierarchical, no serial 50k scan) ----------------
__global__ void deg_kernel(const int* __restrict__ ei, int* __restrict__ deg) {
    int e = blockIdx.x * 256 + threadIdx.x;
    if (e >= N_EDGES) return;
    atomicAdd(&deg[ei[N_EDGES + e]], 1);
}

__global__ void bsum_kernel(const int* __restrict__ deg, int* __restrict__ bcnt) {
    __shared__ int wsum[2];
    int b = blockIdx.x, t = threadIdx.x;
    int n = b * 128 + t;
    int v = (n < N_NODES) ? deg[n] : 0;
#pragma unroll
    for (int off = 1; off < 64; off <<= 1) v += __shfl_xor(v, off);
    if ((t & 63) == 0) wsum[t >> 6] = v;
    __syncthreads();
    if (t == 0) bcnt[b] = wsum[0] + wsum[1];
}

__global__ void scan391_kernel(const int* __restrict__ bcnt, int* __restrict__ bbase,
                               int* __restrict__ bcur) {
    __shared__ int wtot[8];
    int b = threadIdx.x;              // 512 threads, 8 waves
    int lane = b & 63, w = b >> 6;
    int v = (b < NB) ? bcnt[b] : 0;
    int sc = v;
#pragma unroll
    for (int off = 1; off < 64; off <<= 1) {
        int u = __shfl_up(sc, off);
        if (lane >= off) sc += u;
    }
    if (lane == 63) wtot[w] = sc;
    __syncthreads();
    int add = 0;
    for (int k = 0; k < w; ++k) add += wtot[k];
    int excl = sc - v + add;
    if (b < NB) { bbase[b] = excl; bcur[b * 16] = excl; }
    if (b == 0) bbase[NB] = N_EDGES;
}

__global__ void bucket_kernel(const int* __restrict__ ei, int* __restrict__ bcur,
                              unsigned int* __restrict__ stage) {
    int e = blockIdx.x * 256 + threadIdx.x;
    if (e >= N_EDGES) return;
    int src = ei[e], dst = ei[N_EDGES + e];
    int pos = atomicAdd(&bcur[(dst >> 7) * 16], 1);
    stage[pos] = ((unsigned int)(dst & 127) << 16) | (unsigned int)src;
}

__global__ void place_kernel(const int* __restrict__ deg, const int* __restrict__ bbase,
                             const unsigned int* __restrict__ stage,
                             int* __restrict__ rowptr, unsigned short* __restrict__ csr) {
    __shared__ int cur[128];
    __shared__ int wt[2];
    const int b = blockIdx.x;
    const int n0 = b * 128;
    const int t = threadIdx.x;
    const int base = bbase[b];
    const int endp = bbase[b + 1];
    int v = 0, sc = 0;
    if (t < 128) {
        int n = n0 + t;
        v = (n < N_NODES) ? deg[n] : 0;
        int lane = t & 63, w = t >> 6;
        sc = v;
#pragma unroll
        for (int off = 1; off < 64; off <<= 1) {
            int u = __shfl_up(sc, off);
            if (lane >= off) sc += u;
        }
        if (lane == 63) wt[w] = sc;
    }
    __syncthreads();
    if (t < 128) {
        int add = (t >= 64) ? wt[0] : 0;
        int excl = sc - v + add;
        int n = n0 + t;
        if (n <= N_NODES) rowptr[n] = base + excl;   // rowptr[N] emitted by last bucket
        cur[t] = base + excl;
    }
    __syncthreads();
    for (int i = base + t; i < endp; i += 256) {
        unsigned int e = stage[i];
        int pos = atomicAdd(&cur[e >> 16], 1);
        csr[pos] = (unsigned short)(e & 0xFFFFu);
    }
}

// ------- agg layers 1/2 (HC=64): dual-edge half-wave gather -------
__global__ void agg64_kernel(const int* __restrict__ rowptr, const unsigned short* __restrict__ csr_src,
                             const float* __restrict__ al_s, const float* __restrict__ al_d,
                             const unsigned short* __restrict__ hb, const float* __restrict__ b,
                             float* __restrict__ xn) {
    int node = blockIdx.x * 4 + (threadIdx.x >> 6);   // grid exact: N_NODES % 4 == 0
    int lane = threadIdx.x & 63;
    int half = lane >> 5;
    int hl = lane & 31;
    int c0 = hl * 2;
    int hd = hl >> 3;                                 // head = (2*hl)/16
    float ald = al_d[node * 4 + hd];
    int beg = rowptr[node], end = rowptr[node + 1];
    float denom = 0.f, a0 = 0.f, a1 = 0.f;
    if (half == 0) {   // self loop on half 0
        float w = __expf(lrelu02(al_s[node * 4 + hd] + ald));
        float2 p = bfp2(*(const unsigned int*)(hb + (size_t)node * 64 + c0));
        denom = w; a0 = w * p.x; a1 = w * p.y;
    }
    int j = beg + half;
    for (; j + 6 < end; j += 8) {   // 4 edges per half = 8 edges per wave
        int s0 = csr_src[j], s1 = csr_src[j + 2], s2 = csr_src[j + 4], s3 = csr_src[j + 6];
        unsigned int q0 = *(const unsigned int*)(hb + (size_t)s0 * 64 + c0);
        unsigned int q1 = *(const unsigned int*)(hb + (size_t)s1 * 64 + c0);
        unsigned int q2 = *(const unsigned int*)(hb + (size_t)s2 * 64 + c0);
        unsigned int q3 = *(const unsigned int*)(hb + (size_t)s3 * 64 + c0);
        float w0 = __expf(lrelu02(al_s[s0 * 4 + hd] + ald));
        float w1 = __expf(lrelu02(al_s[s1 * 4 + hd] + ald));
        float w2 = __expf(lrelu02(al_s[s2 * 4 + hd] + ald));
        float w3 = __expf(lrelu02(al_s[s3 * 4 + hd] + ald));
        denom += (w0 + w1) + (w2 + w3);
        float2 p;
        p = bfp2(q0); a0 = fmaf(w0, p.x, a0); a1 = fmaf(w0, p.y, a1);
        p = bfp2(q1); a0 = fmaf(w1, p.x, a0); a1 = fmaf(w1, p.y, a1);
        p = bfp2(q2); a0 = fmaf(w2, p.x, a0); a1 = fmaf(w2, p.y, a1);
        p = bfp2(q3); a0 = fmaf(w3, p.x, a0); a1 = fmaf(w3, p.y, a1);
    }
    for (; j < end; j += 2) {
        int s0 = csr_src[j];
        unsigned int q0 = *(const unsigned int*)(hb + (size_t)s0 * 64 + c0);
        float w0 = __expf(lrelu02(al_s[s0 * 4 + hd] + ald));
        denom += w0;
        float2 p = bfp2(q0);
        a0 = fmaf(w0, p.x, a0); a1 = fmaf(w0, p.y, a1);
    }
    denom += __shfl_xor(denom, 32);
    a0 += __shfl_xor(a0, 32);
    a1 += __shfl_xor(a1, 32);
    if (half == 0) {
        float2 o;
        o.x = elu1(a0 / denom + b[c0]);
        o.y = elu1(a1 / denom + b[c0 + 1]);
        *(float2*)(xn + (size_t)node * 64 + c0) = o;
    }
}

// ------- agg layer 3: fp8 gather (uint/lane = 4 ch, 64 lanes = full 256B row); fused final -------
__global__ void agg240_kernel(const int* __restrict__ rowptr, const unsigned short* __restrict__ csr_src,
                              const float* __restrict__ al_s, const float* __restrict__ al_d,
                              const unsigned int* __restrict__ h8, const float* __restrict__ b3,
                              float* __restrict__ y) {
    __shared__ float sh[4][240];
    int wv_id = threadIdx.x >> 6;
    int node = blockIdx.x * 4 + wv_id;                // grid exact: 12500 blocks
    int lane = threadIdx.x & 63;
    bool act = lane < 60;
    int c0 = lane * 4;                                // 0..252 (pad region for lanes 60-63)
    int hd = act ? (c0 / 40) : 5;                     // clamp for pad lanes
    float ald = al_d[node * 6 + hd];
    int beg = rowptr[node], end = rowptr[node + 1];
    float w = __expf(lrelu02(al_s[node * 6 + hd] + ald));
    float denom = w;
    float4 acc;
    {
        unsigned int q = h8[(size_t)node * 64 + lane];
        v2f lo = __builtin_amdgcn_cvt_pk_f32_fp8((int)q, false);
        v2f hi = __builtin_amdgcn_cvt_pk_f32_fp8((int)q, true);
        acc.x = w * lo.x; acc.y = w * lo.y; acc.z = w * hi.x; acc.w = w * hi.y;
    }
    int j = beg;
    for (; j + 8 <= end; j += 8) {
        int s[8];
#pragma unroll
        for (int u = 0; u < 8; ++u) s[u] = csr_src[j + u];
        unsigned int q[8];
#pragma unroll
        for (int u = 0; u < 8; ++u) q[u] = h8[(size_t)s[u] * 64 + lane];
        float wvv[8];
#pragma unroll
        for (int u = 0; u < 8; ++u) wvv[u] = __expf(lrelu02(al_s[s[u] * 6 + hd] + ald));
#pragma unroll
        for (int u = 0; u < 8; ++u) {
            denom += wvv[u];
            v2f lo = __builtin_amdgcn_cvt_pk_f32_fp8((int)q[u], false);
            v2f hi = __builtin_amdgcn_cvt_pk_f32_fp8((int)q[u], true);
            acc.x = fmaf(wvv[u], lo.x, acc.x); acc.y = fmaf(wvv[u], lo.y, acc.y);
            acc.z = fmaf(wvv[u], hi.x, acc.z); acc.w = fmaf(wvv[u], hi.y, acc.w);
        }
    }
    for (; j < end; ++j) {
        int s0 = csr_src[j];
        unsigned int q0 = h8[(size_t)s0 * 64 + lane];
        float w0 = __expf(lrelu02(al_s[s0 * 6 + hd] + ald));
        denom += w0;
        v2f lo = __builtin_amdgcn_cvt_pk_f32_fp8((int)q0, false);
        v2f hi = __builtin_amdgcn_cvt_pk_f32_fp8((int)q0, true);
        acc.x = fmaf(w0, lo.x, acc.x); acc.y = fmaf(w0, lo.y, acc.y);
        acc.z = fmaf(w0, hi.x, acc.z); acc.w = fmaf(w0, hi.y, acc.w);
    }
    if (act) {
        float r = 1.f / denom;
        float* sp = &sh[wv_id][c0];
        sp[0] = acc.x * r; sp[1] = acc.y * r; sp[2] = acc.z * r; sp[3] = acc.w * r;
    }
    __syncthreads();
    float v;
    if (lane < 40) {
        const float* p = sh[wv_id];
        float s = 0.f;
#pragma unroll
        for (int hh = 0; hh < 6; ++hh) s += p[hh * 40 + lane];
        v = elu1(s * (1.f / 6.f) + b3[lane]);
    } else {
        v = -INFINITY;
    }
    float m = v;
#pragma unroll
    for (int o = 32; o > 0; o >>= 1) m = fmaxf(m, __shfl_xor(m, o));
    float ex = (lane < 40) ? __expf(v - m) : 0.f;
    float ssum = ex;
#pragma unroll
    for (int o = 32; o > 0; o >>= 1) ssum += __shfl_xor(ssum, o);
    if (lane < 40) y[(size_t)node * 40 + lane] = v - m - __logf(ssum);
}

extern "C" void kernel_launch(void* const* d_in, const int* in_sizes, int n_in,
                              void* d_out, int out_size, void* d_ws, size_t ws_size,
                              hipStream_t stream) {
    const float* x   = (const float*)d_in[0];
    const int*   ei  = (const int*)d_in[1];   // [2, E]
    const float* W1  = (const float*)d_in[2];
    const float* a1s = (const float*)d_in[3];
    const float* a1d = (const float*)d_in[4];
    const float* b1  = (const float*)d_in[5];
    const float* W2  = (const float*)d_in[6];
    const float* a2s = (const float*)d_in[7];
    const float* a2d = (const float*)d_in[8];
    const float* b2  = (const float*)d_in[9];
    const float* W3  = (const float*)d_in[10];
    const float* a3s = (const float*)d_in[11];
    const float* a3d = (const float*)d_in[12];
    const float* b3  = (const float*)d_in[13];
    float* y = (float*)d_out;

    float* ws = (float*)d_ws;
    unsigned short* h_bf = (unsigned short*)ws;               // 3.2M ushort (layers 1/2)
    float* x_buf   = ws + 1600000;                            // 3,200,000 floats
    float* al_s    = ws + 4800000;                            //   300,000
    float* al_d    = ws + 5100000;                            //   300,000
    unsigned int* h8 = (unsigned int*)(ws + 5400000);         // 3.2M uints (layer-3 fp8, 256B rows)
    int*   deg     = (int*)(ws + 8600000);                    //    50,000
    int*   rowptr  = (int*)(ws + 8650000);                    //    50,001
    unsigned short* csr_src = (unsigned short*)(ws + 8700008);  // 1.6M ushort
    unsigned int* stage = (unsigned int*)(ws + 9500008);      // 1.6M uint
    int* bcur = (int*)(ws + 11100008);                        // NB*16 ints
    int* bcnt = (int*)(ws + 11106264);                        // NB ints
    int* bbase = (int*)(ws + 11106656);                       // NB+1 ints
    // total ~11.11M floats = 44.4 MB

    // ---- CSR build: hierarchical counting sort (no serial 50k scan) ----
    hipMemsetAsync(deg, 0, N_NODES * sizeof(int), stream);
    deg_kernel<<<(N_EDGES + 255) / 256, 256, 0, stream>>>(ei, deg);
    bsum_kernel<<<NB, 128, 0, stream>>>(deg, bcnt);
    scan391_kernel<<<1, 512, 0, stream>>>(bcnt, bbase, bcur);
    bucket_kernel<<<(N_EDGES + 255) / 256, 256, 0, stream>>>(ei, bcur, stage);
    place_kernel<<<NB, 256, 0, stream>>>(deg, bbase, stage, rowptr, csr_src);

    const int agg_grid = N_NODES / 4;              // 12500, exact
    const int gemm_gx = (N_NODES + 31) / 32;
    dim3 gblk(64, 4);

    // ---- layer 1: 128 -> (4,16) concat ----
    gemm_al_kernel<128><<<gemm_gx, gblk, 0, stream>>>(x, W1, a1s, a1d, h_bf, al_s, al_d);
    agg64_kernel<<<agg_grid, 256, 0, stream>>>(rowptr, csr_src, al_s, al_d, h_bf, b1, x_buf);

    // ---- layer 2: 64 -> (4,16) concat ----
    gemm_al_kernel<64><<<gemm_gx, gblk, 0, stream>>>(x_buf, W2, a2s, a2d, h_bf, al_s, al_d);
    agg64_kernel<<<agg_grid, 256, 0, stream>>>(rowptr, csr_src, al_s, al_d, h_bf, b2, x_buf);

    // ---- layer 3: 64 -> (6,40) mean; fp8 h ----
    gemm240_kernel<<<gemm_gx, gblk, 0, stream>>>(x_buf, W3, a3s, a3d, h8, al_s, al_d);
    agg240_kernel<<<agg_grid, 256, 0, stream>>>(rowptr, csr_src, al_s, al_d, h8, b3, y);
}